// Round 11
// baseline (56.973 us; speedup 1.0000x reference)
//
#include <hip/hip_runtime.h>

#define Bq 8
#define Tq 4096
#define Dq 1024
#define NNODES 15

typedef float f32x4 __attribute__((ext_vector_type(4)));

// Kernel A: fused leaf-mean + softmax + mixture partials.
// grid = (b, slice64, rowhalf) = 8*16*2 = 256 blocks, block = 512 (8 waves).
// Block reads x[b, h*1024:(h+1)*1024, d0:d0+64] (256 KiB; 4 rows x 256 B
// contiguous per wave-instr), reduces 4 leaf sums, then writes
// mixpart[h][b][d] = sum_{l=0..3} softmax(nw)[7+4h+l, d] * leafmean.
// Row-half boundary (1024) aligns exactly with leaf boundaries.
__global__ __launch_bounds__(512) void k_leafmix(const float* __restrict__ x,
                                                 const float* __restrict__ nw,
                                                 float* __restrict__ mixpart) {
    const int blk   = blockIdx.x;
    const int b     = blk >> 5;
    const int slice = (blk >> 1) & 15;
    const int h     = blk & 1;
    const int d0    = slice * 64;
    const int t     = threadIdx.x;
    const int qd    = t & 15;       // float4 column within 64-float slice
    const int wv    = t >> 6;       // wave 0..7
    const int lane  = t & 63;
    const int rgl   = lane >> 4;    // row-group-local 0..3
    const int rg    = wv * 4 + rgl; // row group 0..31

    const float4* xb = (const float4*)(x + ((size_t)b * Tq + (size_t)h * 1024) * Dq + d0) + qd;
    float4 acc[4];
#pragma unroll
    for (int l = 0; l < 4; ++l) acc[l] = {0.f, 0.f, 0.f, 0.f};
#pragma unroll
    for (int k = 0; k < 32; ++k) {          // row = rg + 32k; leaf_local = k>>3 (exact)
        const float4 xv = xb[(size_t)(rg + 32 * k) * (Dq / 4)];
        acc[k >> 3].x += xv.x; acc[k >> 3].y += xv.y;
        acc[k >> 3].z += xv.z; acc[k >> 3].w += xv.w;
    }
    // reduce across rgl (lane bits 4,5)
#pragma unroll
    for (int m = 16; m <= 32; m <<= 1)
#pragma unroll
        for (int l = 0; l < 4; ++l) {
            acc[l].x += __shfl_xor(acc[l].x, m, 64);
            acc[l].y += __shfl_xor(acc[l].y, m, 64);
            acc[l].z += __shfl_xor(acc[l].z, m, 64);
            acc[l].w += __shfl_xor(acc[l].w, m, 64);
        }
    __shared__ float lds[8][16][4][4];      // [wave][qd][leaf][comp]
    if (lane < 16) {
#pragma unroll
        for (int l = 0; l < 4; ++l) {
            lds[wv][lane][l][0] = acc[l].x; lds[wv][lane][l][1] = acc[l].y;
            lds[wv][lane][l][2] = acc[l].z; lds[wv][lane][l][3] = acc[l].w;
        }
    }
    __syncthreads();
    if (t < 64) {                            // one d per thread
        const int d  = d0 + t;
        const int q2 = t >> 2, c = t & 3;
        float s[4];
#pragma unroll
        for (int l = 0; l < 4; ++l) {
            float a = lds[0][q2][l][c];
#pragma unroll
            for (int w = 1; w < 8; ++w) a += lds[w][q2][l][c];
            s[l] = a;
        }
        float v[NNODES];
        float m = -1e30f;
#pragma unroll
        for (int n = 0; n < NNODES; ++n) {
            v[n] = nw[n * Dq + d];
            m = fmaxf(m, v[n]);
        }
        float denom = 0.f;
#pragma unroll
        for (int n = 0; n < NNODES; ++n) {
            v[n] = expf(v[n] - m);
            denom += v[n];
        }
        const float inv_denom = 1.0f / denom;
        float mix = 0.f;
#pragma unroll
        for (int l = 0; l < 4; ++l)
            mix += (v[7 + h * 4 + l] * inv_denom) * (s[l] * (1.0f / 256.0f));
        mixpart[((size_t)h * Bq + b) * Dq + d] = mix;
    }
}

// Kernel B: out[b,t,:] = LN(x[b,t,:] + mp0[b,:] + mp1[b,:]) * gamma + beta.
// Wave-per-row, no LDS/barriers, NT stores. Second-half x rows (never reused)
// are loaded nontemporal so they don't evict the L3-warm first half.
__global__ __launch_bounds__(256) void k_ln(const float* __restrict__ x,
                                            const float* __restrict__ mixpart,
                                            const float* __restrict__ gamma,
                                            const float* __restrict__ beta,
                                            float* __restrict__ out) {
    const int wid  = threadIdx.x >> 6;
    const int lane = threadIdx.x & 63;
    const int row  = blockIdx.x * 4 + wid;   // b*T + t
    const int b    = row >> 12;              // T = 4096
    const bool nt2 = (row >> 11) & 1;        // second half of this b's sequence
    const f32x4* xr = (const f32x4*)(x + (size_t)row * Dq);
    const float4* m0 = (const float4*)(mixpart + (size_t)b * Dq);
    const float4* m1 = (const float4*)(mixpart + (size_t)(Bq + b) * Dq);
    float4 o[4];
    float sum = 0.f, sq = 0.f;
#pragma unroll
    for (int k = 0; k < 4; ++k) {
        f32x4 xv;
        if (nt2) xv = __builtin_nontemporal_load(&xr[lane + 64 * k]);
        else     xv = xr[lane + 64 * k];
        const float4 a0 = m0[lane + 64 * k];
        const float4 a1 = m1[lane + 64 * k];
        o[k].x = xv.x + a0.x + a1.x;
        o[k].y = xv.y + a0.y + a1.y;
        o[k].z = xv.z + a0.z + a1.z;
        o[k].w = xv.w + a0.w + a1.w;
        sum += o[k].x + o[k].y + o[k].z + o[k].w;
        sq  += o[k].x * o[k].x + o[k].y * o[k].y + o[k].z * o[k].z + o[k].w * o[k].w;
    }
#pragma unroll
    for (int i = 32; i >= 1; i >>= 1) {
        sum += __shfl_xor(sum, i, 64);
        sq  += __shfl_xor(sq, i, 64);
    }
    const float mu   = sum * (1.0f / 1024.0f);
    const float var  = sq * (1.0f / 1024.0f) - mu * mu;
    const float rstd = rsqrtf(var + 1e-5f);
    f32x4* orow = (f32x4*)(out + (size_t)row * Dq);
#pragma unroll
    for (int k = 0; k < 4; ++k) {
        const float4 gv = ((const float4*)gamma)[lane + 64 * k];
        const float4 bv = ((const float4*)beta)[lane + 64 * k];
        f32x4 r;
        r.x = (o[k].x - mu) * rstd * gv.x + bv.x;
        r.y = (o[k].y - mu) * rstd * gv.y + bv.y;
        r.z = (o[k].z - mu) * rstd * gv.z + bv.z;
        r.w = (o[k].w - mu) * rstd * gv.w + bv.w;
        __builtin_nontemporal_store(r, &orow[lane + 64 * k]);
    }
}

extern "C" void kernel_launch(void* const* d_in, const int* in_sizes, int n_in,
                              void* d_out, int out_size, void* d_ws, size_t ws_size,
                              hipStream_t stream) {
    const float* x     = (const float*)d_in[0];
    // d_in[1] = W_proj, d_in[2] = threshold: numerically dead (all gated states are exactly 0)
    const float* nw    = (const float*)d_in[3];
    const float* gamma = (const float*)d_in[4];
    const float* beta  = (const float*)d_in[5];
    float* out = (float*)d_out;

    float* mixpart = (float*)d_ws;   // 2*8*1024 floats; fully overwritten each call

    k_leafmix<<<Bq * 32, 512, 0, stream>>>(x, nw, mixpart);
    k_ln<<<Bq * Tq / 4, 256, 0, stream>>>(x, mixpart, gamma, beta, out);
}

// Round 12
// 56.680 us; speedup vs baseline: 1.0052x; 1.0052x over previous
//
#include <hip/hip_runtime.h>

#define Bq 8
#define Tq 4096
#define Dq 1024
#define NNODES 15

typedef float f32x4 __attribute__((ext_vector_type(4)));

// Kernel A: fused leaf-mean + softmax + mixture partials.
// grid = (b, slice64, rowhalf) = 8*16*2 = 256 blocks, block = 512 (8 waves).
// Block reads x[b, h*1024:(h+1)*1024, d0:d0+64] (256 KiB; 4 rows x 256 B
// contiguous per wave-instr), reduces 4 leaf sums, then writes
// mixpart[h][b][d] = sum_{l=0..3} softmax(nw)[7+4h+l, d] * leafmean.
// Row-half boundary (1024) aligns exactly with leaf boundaries.
__global__ __launch_bounds__(512) void k_leafmix(const float* __restrict__ x,
                                                 const float* __restrict__ nw,
                                                 float* __restrict__ mixpart) {
    const int blk   = blockIdx.x;
    const int b     = blk >> 5;
    const int slice = (blk >> 1) & 15;
    const int h     = blk & 1;
    const int d0    = slice * 64;
    const int t     = threadIdx.x;
    const int qd    = t & 15;       // float4 column within 64-float slice
    const int wv    = t >> 6;       // wave 0..7
    const int lane  = t & 63;
    const int rgl   = lane >> 4;    // row-group-local 0..3
    const int rg    = wv * 4 + rgl; // row group 0..31

    const float4* xb = (const float4*)(x + ((size_t)b * Tq + (size_t)h * 1024) * Dq + d0) + qd;
    float4 acc[4];
#pragma unroll
    for (int l = 0; l < 4; ++l) acc[l] = {0.f, 0.f, 0.f, 0.f};
#pragma unroll
    for (int k = 0; k < 32; ++k) {          // row = rg + 32k; leaf_local = k>>3 (exact)
        const float4 xv = xb[(size_t)(rg + 32 * k) * (Dq / 4)];
        acc[k >> 3].x += xv.x; acc[k >> 3].y += xv.y;
        acc[k >> 3].z += xv.z; acc[k >> 3].w += xv.w;
    }
    // reduce across rgl (lane bits 4,5)
#pragma unroll
    for (int m = 16; m <= 32; m <<= 1)
#pragma unroll
        for (int l = 0; l < 4; ++l) {
            acc[l].x += __shfl_xor(acc[l].x, m, 64);
            acc[l].y += __shfl_xor(acc[l].y, m, 64);
            acc[l].z += __shfl_xor(acc[l].z, m, 64);
            acc[l].w += __shfl_xor(acc[l].w, m, 64);
        }
    __shared__ float lds[8][16][4][4];      // [wave][qd][leaf][comp]
    if (lane < 16) {
#pragma unroll
        for (int l = 0; l < 4; ++l) {
            lds[wv][lane][l][0] = acc[l].x; lds[wv][lane][l][1] = acc[l].y;
            lds[wv][lane][l][2] = acc[l].z; lds[wv][lane][l][3] = acc[l].w;
        }
    }
    __syncthreads();
    if (t < 64) {                            // one d per thread
        const int d  = d0 + t;
        const int q2 = t >> 2, c = t & 3;
        float s[4];
#pragma unroll
        for (int l = 0; l < 4; ++l) {
            float a = lds[0][q2][l][c];
#pragma unroll
            for (int w = 1; w < 8; ++w) a += lds[w][q2][l][c];
            s[l] = a;
        }
        float v[NNODES];
        float m = -1e30f;
#pragma unroll
        for (int n = 0; n < NNODES; ++n) {
            v[n] = nw[n * Dq + d];
            m = fmaxf(m, v[n]);
        }
        float denom = 0.f;
#pragma unroll
        for (int n = 0; n < NNODES; ++n) {
            v[n] = expf(v[n] - m);
            denom += v[n];
        }
        const float inv_denom = 1.0f / denom;
        float mix = 0.f;
#pragma unroll
        for (int l = 0; l < 4; ++l)
            mix += (v[7 + h * 4 + l] * inv_denom) * (s[l] * (1.0f / 256.0f));
        mixpart[((size_t)h * Bq + b) * Dq + d] = mix;
    }
}

// Kernel B: out[b,t,:] = LN(x[b,t,:] + mp0[b,:] + mp1[b,:]) * gamma + beta.
// Wave-per-row, no LDS/barriers, NT stores. (NT LOADS REMOVED vs R11 —
// single-variable test: they are the suspected -0.9us regression.)
__global__ __launch_bounds__(256) void k_ln(const float* __restrict__ x,
                                            const float* __restrict__ mixpart,
                                            const float* __restrict__ gamma,
                                            const float* __restrict__ beta,
                                            float* __restrict__ out) {
    const int wid  = threadIdx.x >> 6;
    const int lane = threadIdx.x & 63;
    const int row  = blockIdx.x * 4 + wid;   // b*T + t
    const int b    = row >> 12;              // T = 4096
    const float4* xr = (const float4*)(x + (size_t)row * Dq);
    const float4* m0 = (const float4*)(mixpart + (size_t)b * Dq);
    const float4* m1 = (const float4*)(mixpart + (size_t)(Bq + b) * Dq);
    float4 o[4];
    float sum = 0.f, sq = 0.f;
#pragma unroll
    for (int k = 0; k < 4; ++k) {
        const float4 xv = xr[lane + 64 * k];
        const float4 a0 = m0[lane + 64 * k];
        const float4 a1 = m1[lane + 64 * k];
        o[k].x = xv.x + a0.x + a1.x;
        o[k].y = xv.y + a0.y + a1.y;
        o[k].z = xv.z + a0.z + a1.z;
        o[k].w = xv.w + a0.w + a1.w;
        sum += o[k].x + o[k].y + o[k].z + o[k].w;
        sq  += o[k].x * o[k].x + o[k].y * o[k].y + o[k].z * o[k].z + o[k].w * o[k].w;
    }
#pragma unroll
    for (int i = 32; i >= 1; i >>= 1) {
        sum += __shfl_xor(sum, i, 64);
        sq  += __shfl_xor(sq, i, 64);
    }
    const float mu   = sum * (1.0f / 1024.0f);
    const float var  = sq * (1.0f / 1024.0f) - mu * mu;
    const float rstd = rsqrtf(var + 1e-5f);
    f32x4* orow = (f32x4*)(out + (size_t)row * Dq);
#pragma unroll
    for (int k = 0; k < 4; ++k) {
        const float4 gv = ((const float4*)gamma)[lane + 64 * k];
        const float4 bv = ((const float4*)beta)[lane + 64 * k];
        f32x4 r;
        r.x = (o[k].x - mu) * rstd * gv.x + bv.x;
        r.y = (o[k].y - mu) * rstd * gv.y + bv.y;
        r.z = (o[k].z - mu) * rstd * gv.z + bv.z;
        r.w = (o[k].w - mu) * rstd * gv.w + bv.w;
        __builtin_nontemporal_store(r, &orow[lane + 64 * k]);
    }
}

extern "C" void kernel_launch(void* const* d_in, const int* in_sizes, int n_in,
                              void* d_out, int out_size, void* d_ws, size_t ws_size,
                              hipStream_t stream) {
    const float* x     = (const float*)d_in[0];
    // d_in[1] = W_proj, d_in[2] = threshold: numerically dead (all gated states are exactly 0)
    const float* nw    = (const float*)d_in[3];
    const float* gamma = (const float*)d_in[4];
    const float* beta  = (const float*)d_in[5];
    float* out = (float*)d_out;

    float* mixpart = (float*)d_ws;   // 2*8*1024 floats; fully overwritten each call

    k_leafmix<<<Bq * 32, 512, 0, stream>>>(x, nw, mixpart);
    k_ln<<<Bq * Tq / 4, 256, 0, stream>>>(x, mixpart, gamma, beta, out);
}

// Round 13
// 55.382 us; speedup vs baseline: 1.0287x; 1.0234x over previous
//
#include <hip/hip_runtime.h>

#define Bq 8
#define Tq 4096
#define Dq 1024
#define NNODES 15

typedef float f32x4 __attribute__((ext_vector_type(4)));

// Kernel A: fused leaf-mean + softmax + mixture partials.
// R10 geometry (32-float d-slices) split over row-halves for 2 blocks/CU:
// grid = (b=8) x (slice=32) x (h=2) = 512 blocks, block = 512 (8 waves).
// Block reads x[b, h*1024:(h+1)*1024, d0:d0+32] (128 KiB), reduces 4 leaf
// sums (half h covers leaves 4h..4h+3 exactly), writes
// mixpart[h][b][d] = sum_l softmax(nw)[7+4h+l, d] * leafmean.
__global__ __launch_bounds__(512) void k_leafmix(const float* __restrict__ x,
                                                 const float* __restrict__ nw,
                                                 float* __restrict__ mixpart) {
    const int blk   = blockIdx.x;
    const int b     = blk >> 6;
    const int slice = (blk >> 1) & 31;
    const int h     = blk & 1;
    const int d0    = slice * 32;
    const int t     = threadIdx.x;
    const int qd    = t & 7;      // float4 column within 32-float slice
    const int rg    = t >> 3;     // row group 0..63
    const int wv    = t >> 6;     // wave 0..7
    const int lane  = t & 63;

    // rows r = rg + 64*k, k=0..15; leaf_local = k>>2 (exact: 64*(k&3)+rg < 256)
    const float4* xb = (const float4*)(x + ((size_t)b * Tq + (size_t)h * 1024) * Dq + d0) + qd;
    float4 acc[4];
#pragma unroll
    for (int l = 0; l < 4; ++l) acc[l] = {0.f, 0.f, 0.f, 0.f};
#pragma unroll
    for (int k = 0; k < 16; ++k) {
        const float4 xv = xb[(size_t)(rg + 64 * k) * (Dq / 4)];
        acc[k >> 2].x += xv.x; acc[k >> 2].y += xv.y;
        acc[k >> 2].z += xv.z; acc[k >> 2].w += xv.w;
    }
    // in-wave reduction over rg lane-bits 3,4,5 (lanes sharing qd)
#pragma unroll
    for (int m = 8; m <= 32; m <<= 1)
#pragma unroll
        for (int l = 0; l < 4; ++l) {
            acc[l].x += __shfl_xor(acc[l].x, m, 64);
            acc[l].y += __shfl_xor(acc[l].y, m, 64);
            acc[l].z += __shfl_xor(acc[l].z, m, 64);
            acc[l].w += __shfl_xor(acc[l].w, m, 64);
        }
    __shared__ float lds[8][8][4][4];   // [wave][qd][leaf][comp]
    if (lane < 8) {                      // lane == qd representative
#pragma unroll
        for (int l = 0; l < 4; ++l) {
            lds[wv][lane][l][0] = acc[l].x; lds[wv][lane][l][1] = acc[l].y;
            lds[wv][lane][l][2] = acc[l].z; lds[wv][lane][l][3] = acc[l].w;
        }
    }
    __syncthreads();
    if (t < 32) {                        // one d per thread
        const int d  = d0 + t;
        const int q2 = t >> 2, c = t & 3;
        float s[4];
#pragma unroll
        for (int l = 0; l < 4; ++l) {
            float a = lds[0][q2][l][c];
#pragma unroll
            for (int w = 1; w < 8; ++w) a += lds[w][q2][l][c];
            s[l] = a;
        }
        float v[NNODES];
        float m = -1e30f;
#pragma unroll
        for (int n = 0; n < NNODES; ++n) {
            v[n] = nw[n * Dq + d];
            m = fmaxf(m, v[n]);
        }
        float denom = 0.f;
#pragma unroll
        for (int n = 0; n < NNODES; ++n) {
            v[n] = expf(v[n] - m);
            denom += v[n];
        }
        const float inv_denom = 1.0f / denom;
        float mix = 0.f;
#pragma unroll
        for (int l = 0; l < 4; ++l)
            mix += (v[7 + h * 4 + l] * inv_denom) * (s[l] * (1.0f / 256.0f));
        mixpart[((size_t)h * Bq + b) * Dq + d] = mix;
    }
}

// Kernel B: out[b,t,:] = LN(x[b,t,:] + mp0[b,:] + mp1[b,:]) * gamma + beta.
// Wave-per-row, no LDS/barriers, NT stores, regular loads (R12-validated).
__global__ __launch_bounds__(256) void k_ln(const float* __restrict__ x,
                                            const float* __restrict__ mixpart,
                                            const float* __restrict__ gamma,
                                            const float* __restrict__ beta,
                                            float* __restrict__ out) {
    const int wid  = threadIdx.x >> 6;
    const int lane = threadIdx.x & 63;
    const int row  = blockIdx.x * 4 + wid;   // b*T + t
    const int b    = row >> 12;              // T = 4096
    const float4* xr = (const float4*)(x + (size_t)row * Dq);
    const float4* m0 = (const float4*)(mixpart + (size_t)b * Dq);
    const float4* m1 = (const float4*)(mixpart + (size_t)(Bq + b) * Dq);
    float4 o[4];
    float sum = 0.f, sq = 0.f;
#pragma unroll
    for (int k = 0; k < 4; ++k) {
        const float4 xv = xr[lane + 64 * k];
        const float4 a0 = m0[lane + 64 * k];
        const float4 a1 = m1[lane + 64 * k];
        o[k].x = xv.x + a0.x + a1.x;
        o[k].y = xv.y + a0.y + a1.y;
        o[k].z = xv.z + a0.z + a1.z;
        o[k].w = xv.w + a0.w + a1.w;
        sum += o[k].x + o[k].y + o[k].z + o[k].w;
        sq  += o[k].x * o[k].x + o[k].y * o[k].y + o[k].z * o[k].z + o[k].w * o[k].w;
    }
#pragma unroll
    for (int i = 32; i >= 1; i >>= 1) {
        sum += __shfl_xor(sum, i, 64);
        sq  += __shfl_xor(sq, i, 64);
    }
    const float mu   = sum * (1.0f / 1024.0f);
    const float var  = sq * (1.0f / 1024.0f) - mu * mu;
    const float rstd = rsqrtf(var + 1e-5f);
    f32x4* orow = (f32x4*)(out + (size_t)row * Dq);
#pragma unroll
    for (int k = 0; k < 4; ++k) {
        const float4 gv = ((const float4*)gamma)[lane + 64 * k];
        const float4 bv = ((const float4*)beta)[lane + 64 * k];
        f32x4 r;
        r.x = (o[k].x - mu) * rstd * gv.x + bv.x;
        r.y = (o[k].y - mu) * rstd * gv.y + bv.y;
        r.z = (o[k].z - mu) * rstd * gv.z + bv.z;
        r.w = (o[k].w - mu) * rstd * gv.w + bv.w;
        __builtin_nontemporal_store(r, &orow[lane + 64 * k]);
    }
}

extern "C" void kernel_launch(void* const* d_in, const int* in_sizes, int n_in,
                              void* d_out, int out_size, void* d_ws, size_t ws_size,
                              hipStream_t stream) {
    const float* x     = (const float*)d_in[0];
    // d_in[1] = W_proj, d_in[2] = threshold: numerically dead (all gated states are exactly 0)
    const float* nw    = (const float*)d_in[3];
    const float* gamma = (const float*)d_in[4];
    const float* beta  = (const float*)d_in[5];
    float* out = (float*)d_out;

    float* mixpart = (float*)d_ws;   // 2*8*1024 floats; fully overwritten each call

    k_leafmix<<<Bq * 64, 512, 0, stream>>>(x, nw, mixpart);
    k_ln<<<Bq * Tq / 4, 256, 0, stream>>>(x, mixpart, gamma, beta, out);
}